// Round 7
// baseline (572.885 us; speedup 1.0000x reference)
//
#include <hip/hip_runtime.h>

// Problem constants (B=64, T=1000, IN=OUT=512)
//   outputs  zs     [64,1000,512]        -> d_out[0 .. 32768000)
//   states   v_full [64,1001,512]        -> d_out[32768000 .. 65568768)
//   states   z_full [64,1001,512]        -> d_out[65568768 .. 98369536)
#define SV_OFF 32768000
#define SZ_OFF 65568768

typedef __attribute__((ext_vector_type(8))) short bf16x8;
typedef __attribute__((ext_vector_type(4))) float f32x4;

__device__ __forceinline__ unsigned short f2bf(float f) {
  union { float f; unsigned u; } x; x.f = f;
  unsigned r = x.u + 0x7fffu + ((x.u >> 16) & 1u);  // RNE
  return (unsigned short)(r >> 16);
}

__device__ __forceinline__ void gl_lds16(const void* g, void* l) {
  __builtin_amdgcn_global_load_lds(
      (const __attribute__((address_space(1))) unsigned int*)g,
      (__attribute__((address_space(3))) unsigned int*)l, 16, 0, 0);
}

// ---------------------------------------------------------------- prep
__global__ __launch_bounds__(256) void prep(const float* __restrict__ W,
                                            unsigned short* __restrict__ Wb,
                                            int* __restrict__ flags) {
  const int idx = blockIdx.x * 256 + threadIdx.x;
  if (idx < 512 * 512) Wb[idx] = f2bf(W[idx]);
  if (idx < 64) flags[idx] = 0;
}

// ---------------------------------------------------------------- fused cvt+GEMM+scan
// Grid (64,4), 640 threads (10 waves), 1 block/CU. No xb pass: A is read
// DIRECTLY from f32 x with a 2-deep parity-named register pipeline:
//   step s: issue P_{s+2} loads (parity-s regs) -> MFMA -> vmcnt(3)
//   [P_{s+1} landed, ~800cy slack] -> convert+ds_write As[(s+1)&1].
// B via depth-3 global_load_lds from L2-resident Wb (counted, never 0).
// Waves 8-9 scan tile T-1 between tile T's barriers and issue all NT stores.
__global__ __launch_bounds__(640, 1) void fused(
    const float* __restrict__ x,             // [64,1000,512] f32
    const unsigned short* __restrict__ Wb,   // [512,512] bf16
    const float* __restrict__ bias,
    const float* __restrict__ decay,
    float* __restrict__ out,
    int* __restrict__ flags) {
  __shared__ unsigned short As[2][128][32];  // 16 KB (2-buf, reg-fed)
  __shared__ unsigned short Bs[4][128][32];  // 32 KB (gl_lds 4-buf)
  __shared__ float cs[128][128];             // 64 KB (cur tile, swizzled)

  const int b    = blockIdx.x;
  const int o0   = blockIdx.y * 128;
  const int tid  = threadIdx.x;
  const int lane = tid & 63;
  const int wave = tid >> 6;
  const bool gemm = tid < 512;
  const int lr = lane & 15;
  const int lq = lane >> 4;
  const int wr = (wave >> 2) & 1;   // t-half of tile
  const int wc = wave & 3;          // o-quarter of slice

  const int row0 = tid >> 2;        // 0..127 (LDS row this thread stages)
  const int slot = tid & 3;         // 16B-slot within the 64B k-slice
  const int scol = (slot * 16) ^ ((row0 & 3) << 4);          // B src swizzle
  const int awz  = row0 * 64 + ((slot ^ (row0 & 3)) * 16);   // As dst swizzle
  const float* xbase = x + (size_t)b * 512000;
  const char*  bbase = (const char*)Wb + (size_t)o0 * 1024;

#define B_STAGE(s_) do { const int ss_ = (s_) & 127;                            \
    gl_lds16(bbase + (size_t)row0 * 1024 + (ss_ & 15) * 64 + scol,              \
             (char*)&Bs[ss_ & 3][0][0] + tid * 16); } while (0)
#define P_ISSUE(s_, ra, rb) do { const int ss_ = (s_) & 127;                    \
    int rg_ = (ss_ >> 4) * 128 + row0; rg_ = rg_ > 999 ? 999 : rg_;             \
    const float* sp_ = xbase + (size_t)rg_ * 512 + (ss_ & 15) * 32 + slot * 8;  \
    ra = *(const float4*)sp_; rb = *(const float4*)(sp_ + 4); } while (0)
#define A_WRITE(buf_, ra, rb) do { bf16x8 h_;                                   \
    h_[0] = (short)f2bf(ra.x); h_[1] = (short)f2bf(ra.y);                       \
    h_[2] = (short)f2bf(ra.z); h_[3] = (short)f2bf(ra.w);                       \
    h_[4] = (short)f2bf(rb.x); h_[5] = (short)f2bf(rb.y);                       \
    h_[6] = (short)f2bf(rb.z); h_[7] = (short)f2bf(rb.w);                       \
    *(bf16x8*)((char*)&As[buf_][0][0] + awz) = h_; } while (0)

  // scan state (waves 8-9): lane so owns channel o0+so
  const int so = tid - 512;
  float v = 0.f, d = 0.f, om = 0.f, bv = 0.f;
  int fl = 0;
  float4 e0, e1, q0, q1;   // even-parity pair, odd-parity pair

  if (!gemm) {
    d  = decay[o0 + so];
    om = 1.f - d;
    bv = bias[o0 + so];
    __builtin_nontemporal_store(0.f, out + SV_OFF + (size_t)b * 512512 + o0 + so);
    __builtin_nontemporal_store(0.f, out + SZ_OFF + (size_t)b * 512512 + o0 + so);
  } else {
    B_STAGE(0); B_STAGE(1); B_STAGE(2);
    P_ISSUE(0, e0, e1);
    asm volatile("s_waitcnt vmcnt(0)" ::: "memory");   // prologue-only drain
    A_WRITE(0, e0, e1);
    P_ISSUE(1, q0, q1);
    asm volatile("s_waitcnt lgkmcnt(0)" ::: "memory");
  }
  __builtin_amdgcn_s_barrier();
  __builtin_amdgcn_sched_barrier(0);

  // One k-step. iA/iB: regs receiving P_{s+2}; cA/cB: regs of P_{s+1} to convert.
#define STEP_BODY(s_, iA, iB, cA, cB) do {                                      \
    if (gemm) {                                                                 \
      const int ab_ = (s_) & 1;                                                 \
      const int bf_ = (s_) & 3;                                                 \
      const int fo_ = (lq ^ (lr & 3)) * 8;  /* un-swizzle */                    \
      bf16x8 af_[4], bq_[2];                                                    \
      _Pragma("unroll")                                                         \
      for (int i_ = 0; i_ < 4; ++i_)                                            \
        af_[i_] = *(const bf16x8*)(&As[ab_][wr * 64 + i_ * 16 + lr][fo_]);      \
      _Pragma("unroll")                                                         \
      for (int j_ = 0; j_ < 2; ++j_)                                            \
        bq_[j_] = *(const bf16x8*)(&Bs[bf_][wc * 32 + j_ * 16 + lr][fo_]);      \
      B_STAGE((s_) + 3);                                                        \
      P_ISSUE((s_) + 2, iA, iB);                                                \
      __builtin_amdgcn_s_setprio(1);                                            \
      _Pragma("unroll")                                                         \
      for (int i_ = 0; i_ < 4; ++i_)                                            \
        _Pragma("unroll")                                                       \
        for (int j_ = 0; j_ < 2; ++j_)                                          \
          acc[i_][j_] = __builtin_amdgcn_mfma_f32_16x16x32_bf16(                \
              af_[i_], bq_[j_], acc[i_][j_], 0, 0, 0);                          \
      __builtin_amdgcn_s_setprio(0);                                            \
      asm volatile("s_waitcnt vmcnt(3)" ::: "memory");  /* P_{s+1} landed */    \
      A_WRITE(((s_) + 1) & 1, cA, cB);                                          \
      asm volatile("s_waitcnt lgkmcnt(0)" ::: "memory");                        \
    } else if (tile > 0) {                                                      \
      const int pt0_ = (tile - 1) * 128;                                        \
      const int tb_ = ((s_) & 15) * 8;                                          \
      float* zp_ = out + ((size_t)b * 1000 + pt0_ + tb_) * 512 + o0 + so;       \
      float* vp_ = out + SV_OFF + ((size_t)b * 1001 + pt0_ + tb_ + 1) * 512 + o0 + so; \
      float* sp2_ = out + SZ_OFF + ((size_t)b * 1001 + pt0_ + tb_ + 1) * 512 + o0 + so; \
      _Pragma("unroll")                                                         \
      for (int u_ = 0; u_ < 8; ++u_) {                                          \
        const int t_ = tb_ + u_;                                                \
        const float c_ = cs[t_][so ^ (((t_ >> 2) & 3) << 4)];                   \
        v = d * v + om * (c_ + bv);   /* exact reference op order */            \
        const float z_ = (v >= 1.0f) ? 1.0f : 0.0f;                             \
        fl |= (v >= 1.0f);                                                      \
        __builtin_nontemporal_store(z_, zp_ + (size_t)u_ * 512);                \
        __builtin_nontemporal_store(v,  vp_ + (size_t)u_ * 512);                \
        __builtin_nontemporal_store(z_, sp2_ + (size_t)u_ * 512);               \
      }                                                                         \
    }                                                                           \
    __builtin_amdgcn_s_barrier();                                               \
    __builtin_amdgcn_sched_barrier(0);                                          \
  } while (0)

  int s = 0;
  for (int tile = 0; tile < 8; ++tile) {
    f32x4 acc[4][2] = {};
    for (int kk = 0; kk < 16; kk += 2, s += 2) {
      STEP_BODY(s,     e0, e1, q0, q1);   // even: issue->even pair, convert odd
      STEP_BODY(s + 1, q0, q1, e0, e1);   // odd:  issue->odd pair, convert even
    }
    if (gemm) {
      // acc -> cs. Writer col' = col ^ (lq<<4): write ~2-way, read ~2-way
      // (readers recover col via t: stored col' = col ^ (((t>>2)&3)<<4)).
#pragma unroll
      for (int i = 0; i < 4; ++i)
#pragma unroll
        for (int j = 0; j < 2; ++j) {
          const int tb = wr * 64 + i * 16 + lq * 4;
          const int cc = (wc * 32 + j * 16 + lr) ^ (lq << 4);
#pragma unroll
          for (int r = 0; r < 4; ++r) cs[tb + r][cc] = acc[i][j][r];
        }
      asm volatile("s_waitcnt lgkmcnt(0)" ::: "memory");
    }
    __builtin_amdgcn_s_barrier();          // cs(tile) complete & visible
    __builtin_amdgcn_sched_barrier(0);
  }
  // epilogue: scan waves handle tile 7 (104 valid steps); GEMM waves exit.
  if (!gemm) {
    const int pt0 = 896;
    float* zp = out + ((size_t)b * 1000 + pt0) * 512 + o0 + so;
    float* vp = out + SV_OFF + ((size_t)b * 1001 + pt0 + 1) * 512 + o0 + so;
    float* sp = out + SZ_OFF + ((size_t)b * 1001 + pt0 + 1) * 512 + o0 + so;
    for (int t = 0; t < 104; ++t) {
      const float c = cs[t][so ^ (((t >> 2) & 3) << 4)];
      v = d * v + om * (c + bv);
      const float z = (v >= 1.0f) ? 1.0f : 0.0f;
      fl |= (v >= 1.0f);
      __builtin_nontemporal_store(z, zp + (size_t)t * 512);
      __builtin_nontemporal_store(v, vp + (size_t)t * 512);
      __builtin_nontemporal_store(z, sp + (size_t)t * 512);
    }
    if (fl) atomicOr(flags + b, 1);
  }
#undef STEP_BODY
#undef B_STAGE
#undef P_ISSUE
#undef A_WRITE
}

// ---------------------------------------------------------------- fixup (rare path)
// Self-sufficient f32 GEMV fallback; runs only if a batch spiked (never here).
__global__ __launch_bounds__(512) void scan_fix(const float* __restrict__ x,
                                                const float* __restrict__ W,
                                                const float* __restrict__ bias,
                                                const float* __restrict__ R,
                                                const float* __restrict__ decay,
                                                float* __restrict__ out,
                                                const int* __restrict__ flags) {
  const int b = blockIdx.x;
  if (flags[b] == 0) return;
  const int o = threadIdx.x;
  __shared__ float xs[512];
  __shared__ int cnt;
  __shared__ int list[512];
  const float d = decay[o];
  const float om = 1.f - d;
  float v = 0.f, z = 0.f;
  const size_t zb  = (size_t)b * 512000 + o;
  const size_t svb = (size_t)b * 512512 + o;
  float* __restrict__ sv = out + SV_OFF;
  float* __restrict__ sz = out + SZ_OFF;
  sv[svb] = 0.f;
  sz[svb] = 0.f;
  if (o == 0) cnt = 0;
  __syncthreads();
  for (int t = 0; t < 1000; ++t) {
    xs[o] = x[((size_t)b * 1000 + t) * 512 + o];
    __syncthreads();
    float soma = bias[o];
    for (int i = 0; i < 512; ++i) soma += xs[i] * W[(size_t)o * 512 + i];
    const int n = cnt;
    for (int i = 0; i < n; ++i) soma += R[(size_t)o * 512 + list[i]];
    v = d * (v * (1.f - z)) + om * soma;
    z = (v >= 1.0f) ? 1.0f : 0.0f;
    out[zb + (size_t)t * 512] = z;
    sv[svb + (size_t)(t + 1) * 512] = v;
    sz[svb + (size_t)(t + 1) * 512] = z;
    __syncthreads();
    if (o == 0) cnt = 0;
    __syncthreads();
    if (z != 0.f) { const int q = atomicAdd(&cnt, 1); list[q] = o; }
    __syncthreads();
  }
}

extern "C" void kernel_launch(void* const* d_in, const int* in_sizes, int n_in,
                              void* d_out, int out_size, void* d_ws, size_t ws_size,
                              hipStream_t stream) {
  (void)in_sizes; (void)n_in; (void)out_size; (void)ws_size;
  const float* x     = (const float*)d_in[0];  // [64,1000,512]
  const float* W     = (const float*)d_in[1];  // [512,512]
  const float* bias  = (const float*)d_in[2];  // [512]
  const float* R     = (const float*)d_in[3];  // [512,512]
  const float* decay = (const float*)d_in[4];  // [512]
  float* out = (float*)d_out;

  char* ws = (char*)d_ws;
  unsigned short* Wb = (unsigned short*)ws;           //  524,288 B
  int* flags         = (int*)(ws + 524288);           //      256 B

  prep<<<1024, 256, 0, stream>>>(W, Wb, flags);
  fused<<<dim3(64, 4), 640, 0, stream>>>(x, Wb, bias, decay, out, flags);
  scan_fix<<<64, 512, 0, stream>>>(x, W, bias, R, decay, out, flags);
}

// Round 8
// 527.318 us; speedup vs baseline: 1.0864x; 1.0864x over previous
//
#include <hip/hip_runtime.h>

// Problem constants (B=64, T=1000, IN=OUT=512)
//   outputs  zs     [64,1000,512]        -> d_out[0 .. 32768000)
//   states   v_full [64,1001,512]        -> d_out[32768000 .. 65568768)
//   states   z_full [64,1001,512]        -> d_out[65568768 .. 98369536)
#define SV_OFF 32768000
#define SZ_OFF 65568768

typedef __attribute__((ext_vector_type(8))) short bf16x8;
typedef __attribute__((ext_vector_type(4))) float f32x4;

__device__ __forceinline__ unsigned short f2bf(float f) {
  union { float f; unsigned u; } x; x.f = f;
  unsigned r = x.u + 0x7fffu + ((x.u >> 16) & 1u);  // RNE
  return (unsigned short)(r >> 16);
}

__device__ __forceinline__ void gl_lds16(const void* g, void* l) {
  __builtin_amdgcn_global_load_lds(
      (const __attribute__((address_space(1))) unsigned int*)g,
      (__attribute__((address_space(3))) unsigned int*)l, 16, 0, 0);
}

// ---------------------------------------------------------------- prep
__global__ __launch_bounds__(256) void prep(const float* __restrict__ W,
                                            unsigned short* __restrict__ Wb,
                                            int* __restrict__ flags) {
  const int idx = blockIdx.x * 256 + threadIdx.x;
  if (idx < 512 * 512) Wb[idx] = f2bf(W[idx]);
  if (idx < 64) flags[idx] = 0;
}

// ---------------------------------------------------------------- cvt_x
__global__ __launch_bounds__(256) void cvt_x(const float* __restrict__ x,
                                             unsigned short* __restrict__ xb) {
  const size_t i = ((size_t)blockIdx.x * 256 + threadIdx.x) * 8;
  const float4 a = *(const float4*)(x + i);
  const float4 b = *(const float4*)(x + i + 4);
  bf16x8 h;
  h[0] = (short)f2bf(a.x); h[1] = (short)f2bf(a.y);
  h[2] = (short)f2bf(a.z); h[3] = (short)f2bf(a.w);
  h[4] = (short)f2bf(b.x); h[5] = (short)f2bf(b.y);
  h[6] = (short)f2bf(b.z); h[7] = (short)f2bf(b.w);
  *(bf16x8*)(xb + i) = h;
}

// ---------------------------------------------------------------- fused GEMM+scan
// Grid (64,4), 640 threads (10 waves), 1 block/CU.
// Waves 0-7: MFMA GEMM only — depth-3 gl_lds pipeline, counted vmcnt(4)
//   (counts only their own gl_lds; these waves never issue global stores).
// Waves 8-9: scan tile T-1 in 8-timestep chunks inside tile T's 16 k-step
//   barrier intervals, issuing all NT output stores (write drain overlaps).
// Frag-read swizzle: source slot XOR (row>>2)&3 (linear gl_lds dest, same
// XOR on the read) -> each ds_read_b128 maps the wave bijectively onto a
// contiguous 1KB LDS span = minimum 2-way aliasing (free), vs 4-way before.
__global__ __launch_bounds__(640, 1) void fused(
    const unsigned short* __restrict__ Ab,   // xb [64000,512] bf16
    const unsigned short* __restrict__ Wb,   // [512,512] bf16
    const float* __restrict__ bias,
    const float* __restrict__ decay,
    float* __restrict__ out,
    int* __restrict__ flags) {
  __shared__ unsigned short As[4][128][32];  // 32 KB (4-buf k-step pipeline)
  __shared__ unsigned short Bs[4][128][32];  // 32 KB
  __shared__ float cs[128][128];             // 64 KB (cur tile, lq-XOR swizzled)

  const int b    = blockIdx.x;
  const int o0   = blockIdx.y * 128;
  const int tid  = threadIdx.x;
  const int lane = tid & 63;
  const int wave = tid >> 6;
  const bool gemm = tid < 512;
  const int lr = lane & 15;
  const int lq = lane >> 4;
  const int wr = (wave >> 2) & 1;   // t-half of tile
  const int wc = wave & 3;          // o-quarter of slice

  // staging (gemm threads): 512 x 16B per gl_lds = one 8KB k-slice each for
  // As and Bs; linear LDS dest; global source 16B-slot XOR'd by (row>>2)&3.
  const int row0 = tid >> 2;                                   // 0..127
  const int scol = ((tid & 3) ^ ((row0 >> 2) & 3)) * 16;       // swizzled src byte
  const char* abase = (const char*)Ab + (size_t)b * 1000 * 1024;
  const char* bbase = (const char*)Wb + (size_t)o0 * 1024;

#define STAGE(s_) do {                                                          \
    const int t0_ = ((s_) >> 4) * 128;                                          \
    const int kb_ = ((s_) & 15) * 64;                                           \
    const int bf_ = (s_) & 3;                                                   \
    gl_lds16(abase + (size_t)(t0_ + row0) * 1024 + kb_ + scol,                  \
             (char*)&As[bf_][0][0] + tid * 16);                                 \
    gl_lds16(bbase + (size_t)row0 * 1024 + kb_ + scol,                          \
             (char*)&Bs[bf_][0][0] + tid * 16);                                 \
  } while (0)

  // scan state (waves 8-9): lane so = tid-512 owns channel o0+so
  const int so = tid - 512;
  float v = 0.f, d = 0.f, om = 0.f, bv = 0.f;
  int fl = 0;
  if (!gemm) {
    d  = decay[o0 + so];
    om = 1.f - d;
    bv = bias[o0 + so];
    __builtin_nontemporal_store(0.f, out + SV_OFF + (size_t)b * 512512 + o0 + so);
    __builtin_nontemporal_store(0.f, out + SZ_OFF + (size_t)b * 512512 + o0 + so);
  } else {
    STAGE(0); STAGE(1); STAGE(2);   // prologue: 6 loads/wave in flight
  }

  int s = 0;
  for (int tile = 0; tile < 8; ++tile) {
    f32x4 acc[4][2] = {};
    for (int kk = 0; kk < 16; ++kk, ++s) {
      if (gemm)
        asm volatile("s_waitcnt vmcnt(4)" ::: "memory");  // own gl_lds only
      __builtin_amdgcn_s_barrier();
      __builtin_amdgcn_sched_barrier(0);
      if (gemm) {
        // wrap stages (s>=125) are dummies into already-consumed buffers:
        // keeps vmcnt(4) uniform and tail-race-free.
        STAGE((s + 3) & 127);
        const int bf_ = s & 3;
        const int fo = (lq ^ ((lr >> 2) & 3)) * 8;   // un-swizzle (row>>2)&3
        bf16x8 af[4], bq[2];
#pragma unroll
        for (int i = 0; i < 4; ++i)
          af[i] = *(const bf16x8*)(&As[bf_][wr * 64 + i * 16 + lr][fo]);
#pragma unroll
        for (int j = 0; j < 2; ++j)
          bq[j] = *(const bf16x8*)(&Bs[bf_][wc * 32 + j * 16 + lr][fo]);
        __builtin_amdgcn_s_setprio(1);
#pragma unroll
        for (int i = 0; i < 4; ++i)
#pragma unroll
          for (int j = 0; j < 2; ++j)
            acc[i][j] = __builtin_amdgcn_mfma_f32_16x16x32_bf16(af[i], bq[j], acc[i][j], 0, 0, 0);
        __builtin_amdgcn_s_setprio(0);
      } else if (tile > 0) {
        // scan 8 timesteps of tile-1 (cs holds tile-1 until the pre-write
        // barrier below; chunks kk=0..15 cover t=0..127)
        const int pt0 = (tile - 1) * 128;
        const int tb = kk * 8;
        float* zp = out + ((size_t)b * 1000 + pt0 + tb) * 512 + o0 + so;
        float* vp = out + SV_OFF + ((size_t)b * 1001 + pt0 + tb + 1) * 512 + o0 + so;
        float* sp = out + SZ_OFF + ((size_t)b * 1001 + pt0 + tb + 1) * 512 + o0 + so;
#pragma unroll
        for (int u = 0; u < 8; ++u) {
          const int t = tb + u;
          const float c = cs[t][so ^ (((t >> 2) & 3) << 4)];
          v = d * v + om * (c + bv);   // exact reference op order (no-spike path)
          const float z = (v >= 1.0f) ? 1.0f : 0.0f;
          fl |= (v >= 1.0f);
          __builtin_nontemporal_store(z, zp + (size_t)u * 512);
          __builtin_nontemporal_store(v, vp + (size_t)u * 512);
          __builtin_nontemporal_store(z, sp + (size_t)u * 512);
        }
      }
    }
    __builtin_amdgcn_s_barrier();          // scan chunk 15 done reading cs
    __builtin_amdgcn_sched_barrier(0);
    if (gemm) {
      // acc -> cs. Writer col' = col ^ (lq<<4): write ~2-way, read ~2-way
      // (lq = (row>>2)&3 for every row this lane writes; readers recover
      //  col via t: stored col' = col ^ (((t>>2)&3)<<4)).
#pragma unroll
      for (int i = 0; i < 4; ++i)
#pragma unroll
        for (int j = 0; j < 2; ++j) {
          const int tb = wr * 64 + i * 16 + lq * 4;
          const int cc = (wc * 32 + j * 16 + lr) ^ (lq << 4);
#pragma unroll
          for (int r = 0; r < 4; ++r) cs[tb + r][cc] = acc[i][j][r];
        }
      asm volatile("s_waitcnt lgkmcnt(0)" ::: "memory");
    }
    __builtin_amdgcn_s_barrier();          // cs(tile) complete & visible
    __builtin_amdgcn_sched_barrier(0);
  }
  // epilogue: scan waves handle tile 7 (104 valid steps); GEMM waves exit.
  if (!gemm) {
    const int pt0 = 896;
    float* zp = out + ((size_t)b * 1000 + pt0) * 512 + o0 + so;
    float* vp = out + SV_OFF + ((size_t)b * 1001 + pt0 + 1) * 512 + o0 + so;
    float* sp = out + SZ_OFF + ((size_t)b * 1001 + pt0 + 1) * 512 + o0 + so;
    for (int t = 0; t < 104; ++t) {
      const float c = cs[t][so ^ (((t >> 2) & 3) << 4)];
      v = d * v + om * (c + bv);
      const float z = (v >= 1.0f) ? 1.0f : 0.0f;
      fl |= (v >= 1.0f);
      __builtin_nontemporal_store(z, zp + (size_t)t * 512);
      __builtin_nontemporal_store(v, vp + (size_t)t * 512);
      __builtin_nontemporal_store(z, sp + (size_t)t * 512);
    }
    if (fl) atomicOr(flags + b, 1);
  }
#undef STAGE
}

// ---------------------------------------------------------------- fixup (rare path)
// Self-sufficient f32 GEMV fallback; runs only if a batch spiked (never here).
__global__ __launch_bounds__(512) void scan_fix(const float* __restrict__ x,
                                                const float* __restrict__ W,
                                                const float* __restrict__ bias,
                                                const float* __restrict__ R,
                                                const float* __restrict__ decay,
                                                float* __restrict__ out,
                                                const int* __restrict__ flags) {
  const int b = blockIdx.x;
  if (flags[b] == 0) return;
  const int o = threadIdx.x;
  __shared__ float xs[512];
  __shared__ int cnt;
  __shared__ int list[512];
  const float d = decay[o];
  const float om = 1.f - d;
  float v = 0.f, z = 0.f;
  const size_t zb  = (size_t)b * 512000 + o;
  const size_t svb = (size_t)b * 512512 + o;
  float* __restrict__ sv = out + SV_OFF;
  float* __restrict__ sz = out + SZ_OFF;
  sv[svb] = 0.f;
  sz[svb] = 0.f;
  if (o == 0) cnt = 0;
  __syncthreads();
  for (int t = 0; t < 1000; ++t) {
    xs[o] = x[((size_t)b * 1000 + t) * 512 + o];
    __syncthreads();
    float soma = bias[o];
    for (int i = 0; i < 512; ++i) soma += xs[i] * W[(size_t)o * 512 + i];
    const int n = cnt;
    for (int i = 0; i < n; ++i) soma += R[(size_t)o * 512 + list[i]];
    v = d * (v * (1.f - z)) + om * soma;
    z = (v >= 1.0f) ? 1.0f : 0.0f;
    out[zb + (size_t)t * 512] = z;
    sv[svb + (size_t)(t + 1) * 512] = v;
    sz[svb + (size_t)(t + 1) * 512] = z;
    __syncthreads();
    if (o == 0) cnt = 0;
    __syncthreads();
    if (z != 0.f) { const int q = atomicAdd(&cnt, 1); list[q] = o; }
    __syncthreads();
  }
}

extern "C" void kernel_launch(void* const* d_in, const int* in_sizes, int n_in,
                              void* d_out, int out_size, void* d_ws, size_t ws_size,
                              hipStream_t stream) {
  (void)in_sizes; (void)n_in; (void)out_size; (void)ws_size;
  const float* x     = (const float*)d_in[0];  // [64,1000,512]
  const float* W     = (const float*)d_in[1];  // [512,512]
  const float* bias  = (const float*)d_in[2];  // [512]
  const float* R     = (const float*)d_in[3];  // [512,512]
  const float* decay = (const float*)d_in[4];  // [512]
  float* out = (float*)d_out;

  char* ws = (char*)d_ws;
  unsigned short* xb = (unsigned short*)ws;                 // 65,536,000 B
  unsigned short* Wb = (unsigned short*)(ws + 65536000);    //    524,288 B
  int* flags         = (int*)(ws + 66060288);               //        256 B
  // (OOB-safe: b=63 tile-7 pad rows read <=25 KB into the Wb region)

  prep<<<1024, 256, 0, stream>>>(W, Wb, flags);
  cvt_x<<<16000, 256, 0, stream>>>(x, xb);
  fused<<<dim3(64, 4), 640, 0, stream>>>(xb, Wb, bias, decay, out, flags);
  scan_fix<<<64, 512, 0, stream>>>(x, W, bias, R, decay, out, flags);
}